// Round 1
// baseline (264.337 us; speedup 1.0000x reference)
//
#include <hip/hip_runtime.h>
#include <math.h>

// EnergySRB: srb = pre[s0,s1] * exp(dfac[s0,s1]*d_bohr) * smooth_cutoff(d_bohr, rc)
// out[mol] = energies[mol] + segment_sum(srb, mol = atom0 // n_atoms)
// Output tuple: (species as float, energies_out) concatenated in d_out.

// ---------------------------------------------------------------------------
// Kernel 1: pack species (values 0..3) into 2-bit words. 262144 atoms -> 64KB.
__global__ void pack_species_kernel(const int* __restrict__ sp,
                                    unsigned* __restrict__ packed, int nwords) {
    int w = blockIdx.x * blockDim.x + threadIdx.x;
    if (w >= nwords) return;
    const int4* p4 = (const int4*)(sp + (w << 4));
    int4 a = p4[0], b = p4[1], c = p4[2], d = p4[3];
    unsigned v =
        (unsigned)(a.x & 3)        | ((unsigned)(a.y & 3) << 2)  |
        ((unsigned)(a.z & 3) << 4) | ((unsigned)(a.w & 3) << 6)  |
        ((unsigned)(b.x & 3) << 8) | ((unsigned)(b.y & 3) << 10) |
        ((unsigned)(b.z & 3) << 12)| ((unsigned)(b.w & 3) << 14) |
        ((unsigned)(c.x & 3) << 16)| ((unsigned)(c.y & 3) << 18) |
        ((unsigned)(c.z & 3) << 20)| ((unsigned)(c.w & 3) << 22) |
        ((unsigned)(d.x & 3) << 24)| ((unsigned)(d.y & 3) << 26) |
        ((unsigned)(d.z & 3) << 28)| ((unsigned)(d.w & 3) << 30);
    packed[w] = v;
}

// ---------------------------------------------------------------------------
// Kernel 2: initialize d_out: [0, n_species) = (float)species,
//                             [n_species, n_species+n_mol) = energies.
__global__ void init_out_kernel(const int* __restrict__ species,
                                const float* __restrict__ energies,
                                float* __restrict__ out,
                                int n_species, int n_mol) {
    int i = blockIdx.x * blockDim.x + threadIdx.x;
    if (i < n_species) {
        out[i] = (float)species[i];
    } else if (i < n_species + n_mol) {
        out[i] = energies[i - n_species];
    }
}

// ---------------------------------------------------------------------------
// Kernel 3: the pair kernel.
// LDS: 64KB packed species (random gathers stay on-chip) + 16KB mol bins
//      (segment_sum without global atomic storms) + 128B fused tables.
// 1024 threads/block, 82KB LDS -> 1 block/CU, 16 waves/CU.
template <bool FROM_WS>
__global__ __launch_bounds__(1024, 1)
void srb_main_kernel(const unsigned* __restrict__ packed_ws,
                     const int* __restrict__ species,
                     const int* __restrict__ ai,     // [2, P]
                     const float* __restrict__ dist, // [P] angstrom
                     const float* __restrict__ pre_tab,   // 16 floats
                     const float* __restrict__ dfac_tab,  // 16 floats
                     float* __restrict__ out_e,      // [n_mol]
                     int P, int mol_shift) {
    __shared__ unsigned packed[16384]; // 64KB: 2-bit species, all 262144 atoms
    __shared__ float bins[4096];       // 16KB: per-molecule partial sums
    __shared__ float2 tab[16];         // (pre, dfac) per species pair

    const int t  = threadIdx.x;
    const int NT = blockDim.x;

    for (int i = t; i < 4096; i += NT) bins[i] = 0.0f;
    if (t < 16) tab[t] = make_float2(pre_tab[t], dfac_tab[t]);

    if (FROM_WS) {
        int4* dst = (int4*)packed;
        const int4* src = (const int4*)packed_ws;
        for (int i = t; i < 4096; i += NT) dst[i] = src[i];
    } else {
        // fallback: pack directly from global species (1MB read per block)
        for (int w = t; w < 16384; w += NT) {
            const int4* p4 = (const int4*)(species + (w << 4));
            int4 a = p4[0], b = p4[1], c = p4[2], d = p4[3];
            unsigned v =
                (unsigned)(a.x & 3)        | ((unsigned)(a.y & 3) << 2)  |
                ((unsigned)(a.z & 3) << 4) | ((unsigned)(a.w & 3) << 6)  |
                ((unsigned)(b.x & 3) << 8) | ((unsigned)(b.y & 3) << 10) |
                ((unsigned)(b.z & 3) << 12)| ((unsigned)(b.w & 3) << 14) |
                ((unsigned)(c.x & 3) << 16)| ((unsigned)(c.y & 3) << 18) |
                ((unsigned)(c.z & 3) << 20)| ((unsigned)(c.w & 3) << 22) |
                ((unsigned)(d.x & 3) << 24)| ((unsigned)(d.y & 3) << 26) |
                ((unsigned)(d.z & 3) << 28)| ((unsigned)(d.w & 3) << 30);
            packed[w] = v;
        }
    }
    __syncthreads();

    // Constants computed in double then rounded once, matching numpy's
    // float32-with-python-scalar weak promotion.
    const float a2b   = (float)1.8897261258369282;
    const float rc    = (float)(5.2 * 1.8897261258369282);
    const float rcinv = (float)(1.0 / (5.2 * 1.8897261258369282));

    const int* ai0 = ai;
    const int* ai1 = ai + P;

    auto body = [&](int a0, int a1, float dang) {
        unsigned w0 = packed[(unsigned)a0 >> 4];
        unsigned w1 = packed[(unsigned)a1 >> 4];
        unsigned s0 = (w0 >> (((unsigned)a0 & 15u) << 1)) & 3u;
        unsigned s1 = (w1 >> (((unsigned)a1 & 15u) << 1)) & 3u;
        float2 td = tab[(s0 << 2) | s1];
        float db = dang * a2b;
        if (db < rc) {
            // fused exponent: exp(dfac*d) * exp(1 - 1/(1-x2)) = exp(sum)
            float x  = db * rcinv;
            float x2 = x * x;
            float arg = td.y * db + (1.0f - 1.0f / (1.0f - x2));
            float srb = td.x * __expf(arg);
            atomicAdd(&bins[(unsigned)a0 >> mol_shift], srb);
        }
        // db >= rc contributes exactly 0 (matches reference's where()).
    };

    const int stride = (int)gridDim.x * NT;
    if ((P & 3) == 0) {
        const int nvec = P >> 2;
        const int4*   v0 = (const int4*)ai0;
        const int4*   v1 = (const int4*)ai1;
        const float4* dv = (const float4*)dist;
        for (int v = (int)blockIdx.x * NT + t; v < nvec; v += stride) {
            int4   i0 = v0[v];
            int4   i1 = v1[v];
            float4 dd = dv[v];
            body(i0.x, i1.x, dd.x);
            body(i0.y, i1.y, dd.y);
            body(i0.z, i1.z, dd.z);
            body(i0.w, i1.w, dd.w);
        }
    } else {
        for (int p = (int)blockIdx.x * NT + t; p < P; p += stride)
            body(ai0[p], ai1[p], dist[p]);
    }

    __syncthreads();
    for (int i = t; i < 4096; i += NT) {
        float s = bins[i];
        if (s != 0.0f) atomicAdd(&out_e[i], s);
    }
}

// ---------------------------------------------------------------------------
extern "C" void kernel_launch(void* const* d_in, const int* in_sizes, int n_in,
                              void* d_out, int out_size, void* d_ws, size_t ws_size,
                              hipStream_t stream) {
    const int*   species  = (const int*)d_in[0];
    const float* energies = (const float*)d_in[1];
    const int*   ai       = (const int*)d_in[2];
    const float* dist     = (const float*)d_in[3];
    const float* pre_tab  = (const float*)d_in[4];
    const float* dfac_tab = (const float*)d_in[5];

    const int n_species = in_sizes[0];            // 262144
    const int n_mol     = in_sizes[1];            // 4096
    const int P         = in_sizes[3];            // 16777216
    const int n_atoms   = n_species / n_mol;      // 64 (power of two)

    int mol_shift = 0;
    while ((1 << mol_shift) < n_atoms) ++mol_shift; // 6

    float* out   = (float*)d_out;
    float* out_e = out + n_species;

    // 1) init output (species passthrough + energies)
    {
        int tot = n_species + n_mol;
        init_out_kernel<<<(tot + 255) / 256, 256, 0, stream>>>(
            species, energies, out, n_species, n_mol);
    }

    // 2+3) pack species then main pair kernel
    const int nwords = n_species / 16; // 16384
    const bool use_ws = ws_size >= (size_t)nwords * sizeof(unsigned);
    if (use_ws) {
        unsigned* packed = (unsigned*)d_ws;
        pack_species_kernel<<<(nwords + 255) / 256, 256, 0, stream>>>(
            species, packed, nwords);
        srb_main_kernel<true><<<256, 1024, 0, stream>>>(
            packed, species, ai, dist, pre_tab, dfac_tab, out_e, P, mol_shift);
    } else {
        srb_main_kernel<false><<<256, 1024, 0, stream>>>(
            nullptr, species, ai, dist, pre_tab, dfac_tab, out_e, P, mol_shift);
    }
}